// Round 8
// baseline (290.311 us; speedup 1.0000x reference)
//
#include <hip/hip_runtime.h>
#include <stdint.h>

#define NNODES 100000
#define NEDGES 100000
#define DIM    256
#define NCH    4          // 2 side + 2 rel
#define ET     64         // edges per tile
#define NT     1563       // ceil(NEDGES / ET)
#define NBX    64         // blocks per channel; each block strides tiles by NBX
#define RSF    264        // fp16 per staged row (256 + 8 pad)
#define CONVB  2048       // grid-stride conversion blocks
#define ZEROB  391        // out-zeroing blocks (391*256*4 >= 400000 floats)

typedef _Float16 f16x8 __attribute__((ext_vector_type(8)));
typedef _Float16 f16x4 __attribute__((ext_vector_type(4)));
typedef float f32x4  __attribute__((ext_vector_type(4)));

// ---------------------------------------------------------------------------
// Fused prep: B tables (hi/lo fp16, MFMA B-fragment order) + h f32->fp16
// conversion + ZERO the output buffer (edge kernel now accumulates into out
// with atomicAdd, so out must start at 0; same-stream launch order makes
// this safe).
// ---------------------------------------------------------------------------
__global__ void prep_fused(const float* __restrict__ RW,
                           const float* __restrict__ dside,
                           const float* __restrict__ Wrel,
                           const float* __restrict__ h,
                           _Float16* __restrict__ Bh, _Float16* __restrict__ Bl,
                           _Float16* __restrict__ H16,
                           float* __restrict__ out) {
    if (blockIdx.x < 128) {
        int t = blockIdx.x * blockDim.x + threadIdx.x;   // < 32768
        int lane = t & 63;
        int ft   = (t >> 6) & 15;
        int kc   = (t >> 10) & 7;
        int c    = t >> 13;
        int quad = lane >> 4, col = lane & 15;
        int f     = ft * 16 + col;
        int kbase = kc * 32 + quad * 8;

        f16x8 vh, vl;
#pragma unroll
        for (int j = 0; j < 8; ++j) {
            int k = kbase + j;
            float val;
            if (c < 2) {
                val = dside[c * DIM + f] * RW[f * DIM + k] * dside[c * DIM + k];
            } else {
                val = Wrel[(size_t)(c - 2) * DIM * DIM + f * DIM + k];
            }
            _Float16 hi = (_Float16)val;
            vh[j] = hi;
            vl[j] = (_Float16)(val - (float)hi);
        }
        ((f16x8*)Bh)[t] = vh;
        ((f16x8*)Bl)[t] = vl;
    } else if (blockIdx.x < 128 + ZEROB) {
        int i4 = (blockIdx.x - 128) * 256 + (int)threadIdx.x;   // f32x4 chunks
        if (i4 < NCH * NEDGES / 4)
            ((f32x4*)out)[i4] = (f32x4){0.f, 0.f, 0.f, 0.f};
    } else {
        const int total4 = NNODES * DIM / 4;   // 6.4e6 f32x4 chunks
        const int stride = CONVB * 256;
        int i = (blockIdx.x - 128 - ZEROB) * 256 + (int)threadIdx.x;
        const f32x4* s4 = (const f32x4*)h;
        f16x4* d4 = (f16x4*)H16;
        for (; i + stride < total4; i += 2 * stride) {
            f32x4 a = s4[i];
            f32x4 b = s4[i + stride];
            f16x4 oa, ob;
#pragma unroll
            for (int j = 0; j < 4; ++j) { oa[j] = (_Float16)a[j]; ob[j] = (_Float16)b[j]; }
            d4[i] = oa; d4[i + stride] = ob;
        }
        if (i < total4) {
            f32x4 a = s4[i];
            f16x4 o;
#pragma unroll
            for (int j = 0; j < 4; ++j) o[j] = (_Float16)a[j];
            d4[i] = o;
        }
    }
}

// 16-lane-row sum reduction on the VALU via DPP (confirmed round-7 win).
// After 4 steps EVERY lane in the 16-group holds the 16-sum.
__device__ __forceinline__ float dpp_reduce16(float s) {
    union { float f; int i; } u, v;
    u.f = s; v.i = __builtin_amdgcn_update_dpp(0, u.i, 0xB1,  0xF, 0xF, true); s += v.f;
    u.f = s; v.i = __builtin_amdgcn_update_dpp(0, u.i, 0x4E,  0xF, 0xF, true); s += v.f;
    u.f = s; v.i = __builtin_amdgcn_update_dpp(0, u.i, 0x141, 0xF, 0xF, true); s += v.f;
    u.f = s; v.i = __builtin_amdgcn_update_dpp(0, u.i, 0x140, 0xF, 0xF, true); s += v.f;
    return s;
}

// ---------------------------------------------------------------------------
// Edge kernel v8: ONE barrier per tile (was 2) via LDS double-buffer +
// atomic epilogue (red[] exchange removed).
//  ROUND-7 LESSON (model confirmed): kernel is DS/overlap-bound. The two
//  barriers per tile split the overlap window; every wave's ~4Kcy
//  epilogue+stage phase left the MFMA pipe idle (38% util).
//  Hazard proof for 1 barrier: stage_k writes buf[k&1]; the only readers
//  of buf[k&1] before it are Kloop/epi_{k-2}, and barrier_{k-1} (passed by
//  every wave before its stage_k) orders all of iter k-2 before stage_k.
//  Cross-wave: stage_k vs Kloop/epi_{k-1} touch opposite buffers.
//  Epilogue: dpp_reduce16 leaves the full 16-sum in ALL lanes; lanes with
//  col==0 (4/wave) atomicAdd the 16 (mt,r) sums into out (8 adds/output
//  across waves; order-change rounding ~1e-5, tolerance has margin).
//  Also: __shfl -> readlane for idx redistribution (SALU, not ds_bpermute).
// ---------------------------------------------------------------------------
__global__ __launch_bounds__(512, 1)
void edge_kernel(const _Float16* __restrict__ H16,
                 const int* __restrict__ src_idx,
                 const int* __restrict__ dst_idx,
                 const float* __restrict__ brel,
                 const _Float16* __restrict__ Bh_sw,
                 const _Float16* __restrict__ Bl_sw,
                 float* __restrict__ out) {
    const int c    = blockIdx.y;
    const int tid  = threadIdx.x;
    const int w    = tid >> 6;          // 0..7
    const int lane = tid & 63;
    const int quad = lane >> 4, col = lane & 15;

    __shared__ __align__(16) _Float16 s_a0[ET * RSF];   // 33,792 B each
    __shared__ __align__(16) _Float16 s_v0[ET * RSF];
    __shared__ __align__(16) _Float16 s_a1[ET * RSF];
    __shared__ __align__(16) _Float16 s_v1[ET * RSF];   // total 135,168 B

    // ---- B registers: wave w holds ft = {2w, 2w+1}, all kc, hi+lo ----
    f16x8 Bh_r[8][2], Bl_r[8][2];
    {
        const f16x8* bh = (const f16x8*)Bh_sw;
        const f16x8* bl = (const f16x8*)Bl_sw;
#pragma unroll
        for (int kc = 0; kc < 8; ++kc)
#pragma unroll
            for (int ftl = 0; ftl < 2; ++ftl) {
                int o = ((c * 8 + kc) * 16 + (w * 2 + ftl)) * 64 + lane;
                Bh_r[kc][ftl] = bh[o];
                Bl_r[kc][ftl] = bl[o];
            }
    }
#pragma unroll
    for (int kc = 0; kc < 8; ++kc)
#pragma unroll
        for (int ftl = 0; ftl < 2; ++ftl)
            asm volatile("" : "+v"(Bh_r[kc][ftl]), "+v"(Bl_r[kc][ftl]));

    float bias[2];
#pragma unroll
    for (int ftl = 0; ftl < 2; ++ftl) {
        int f = (w * 2 + ftl) * 16 + col;
        bias[ftl] = (c >= 2) ? brel[(size_t)(c - 2) * DIM + f] : 0.f;
    }

    // Lane-packed index loads: lanes 0..7 -> src idx of rows w*8+0..7,
    // lanes 8..15 -> dst idx.
    const int  j8   = lane & 7;
    const bool isV  = (lane & 8) != 0;
    const int* ibase = (isV ? dst_idx : src_idx) + (size_t)c * NEDGES;

    auto loadpack = [&](int t) -> int {
        int e = t * ET + w * 8 + j8;
        if (e >= NEDGES) e = NEDGES - 1;
        return ibase[e];
    };

    // ---- Prologue: gather tile t0 rows; preload idx pack for t0+NBX ----
    const int t0 = blockIdx.x;
    f16x4 pA[8], pV[8];
    {
        int ip = loadpack(t0);
#pragma unroll
        for (int i = 0; i < 8; ++i) {
            int ia = __builtin_amdgcn_readlane(ip, i);
            int iv = __builtin_amdgcn_readlane(ip, 8 + i);
            pA[i] = *(const f16x4*)(H16 + (size_t)ia * DIM + lane * 4);
            pV[i] = *(const f16x4*)(H16 + (size_t)iv * DIM + lane * 4);
        }
    }
    int ipk0 = 0, ipk1 = 0;
    if (t0 + NBX < NT) ipk1 = loadpack(t0 + NBX);

    // ---- Tile body: {stage; issue next gathers; BARRIER; K-loop; epi} ----
    auto body = [&](int t, _Float16* sa, _Float16* sv, int& ipkUse, int& ipkLoad) {
        // stage tile t rows (gathered during previous tile) into this
        // iteration's buffer pair
#pragma unroll
        for (int i = 0; i < 8; ++i) {
            int lr = w * 8 + i;
            *(f16x4*)&sa[lr * RSF + lane * 4] = pA[i];
            *(f16x4*)&sv[lr * RSF + lane * 4] = pV[i];
        }

        // issue idx loads 2 tiles ahead, row gathers 1 tile ahead (T14)
        if (t + 2 * NBX < NT) ipkLoad = loadpack(t + 2 * NBX);
        if (t + NBX < NT) {
#pragma unroll
            for (int i = 0; i < 8; ++i) {
                int ia = __builtin_amdgcn_readlane(ipkUse, i);
                int iv = __builtin_amdgcn_readlane(ipkUse, 8 + i);
                pA[i] = *(const f16x4*)(H16 + (size_t)ia * DIM + lane * 4);
                pV[i] = *(const f16x4*)(H16 + (size_t)iv * DIM + lane * 4);
            }
        }

        __syncthreads();   // the ONLY barrier this tile

        // K-loop: A from LDS, B from registers (AGPR-resident), 2-term MFMA
        f32x4 acc[4][2];
#pragma unroll
        for (int mt = 0; mt < 4; ++mt)
#pragma unroll
            for (int ftl = 0; ftl < 2; ++ftl) acc[mt][ftl] = (f32x4){0.f, 0.f, 0.f, 0.f};

#pragma unroll
        for (int kc = 0; kc < 8; ++kc) {
            f16x8 A[4];
#pragma unroll
            for (int mt = 0; mt < 4; ++mt)
                A[mt] = *(const f16x8*)&sa[(mt * 16 + col) * RSF + kc * 32 + quad * 8];
#pragma unroll
            for (int ftl = 0; ftl < 2; ++ftl) {
#pragma unroll
                for (int mt = 0; mt < 4; ++mt)
                    acc[mt][ftl] = __builtin_amdgcn_mfma_f32_16x16x32_f16(A[mt], Bh_r[kc][ftl], acc[mt][ftl], 0, 0, 0);
#pragma unroll
                for (int mt = 0; mt < 4; ++mt)
                    acc[mt][ftl] = __builtin_amdgcn_mfma_f32_16x16x32_f16(A[mt], Bl_r[kc][ftl], acc[mt][ftl], 0, 0, 0);
            }
        }

        // Epilogue: score contribution = sum over this wave's 32 f-cols of
        // (C[e][f] + bias[f]) * V[e][f]; DPP-reduced, atomically accumulated.
#pragma unroll
        for (int mt = 0; mt < 4; ++mt) {
            float ps[4];
#pragma unroll
            for (int r = 0; r < 4; ++r) {
                int el = mt * 16 + quad * 4 + r;
                float s = 0.f;
#pragma unroll
                for (int ftl = 0; ftl < 2; ++ftl) {
                    int f = (w * 2 + ftl) * 16 + col;
                    float v = (float)sv[el * RSF + f];
                    s += (acc[mt][ftl][r] + bias[ftl]) * v;
                }
                ps[r] = dpp_reduce16(s);
            }
            if (col == 0) {
#pragma unroll
                for (int r = 0; r < 4; ++r) {
                    int e = t * ET + mt * 16 + quad * 4 + r;
                    if (e < NEDGES)
                        atomicAdd(&out[(size_t)c * NEDGES + e], ps[r]);
                }
            }
        }
        // no second barrier: next iteration's barrier orders this epilogue's
        // buffer reads against the stage writes two iterations out.
    };

    int t = t0;
    while (true) {
        body(t, s_a0, s_v0, ipk1, ipk0);            // parity 0
        t += NBX; if (t >= NT) break;
        body(t, s_a1, s_v1, ipk0, ipk1);            // parity 1
        t += NBX; if (t >= NT) break;
    }
}

extern "C" void kernel_launch(void* const* d_in, const int* in_sizes, int n_in,
                              void* d_out, int out_size, void* d_ws, size_t ws_size,
                              hipStream_t stream) {
    const float* hmat  = (const float*)d_in[0];
    const int*   src   = (const int*)d_in[1];
    const int*   dst   = (const int*)d_in[2];
    const float* RW    = (const float*)d_in[3];
    const float* dside = (const float*)d_in[4];
    const float* Wrel  = (const float*)d_in[5];
    const float* brel  = (const float*)d_in[6];
    float* out = (float*)d_out;

    // Workspace: Bh (512 KB) | Bl (512 KB) | H16 (51.2 MB)
    const size_t nB = (size_t)NCH * DIM * DIM;   // fp16 per table
    _Float16* Bh  = (_Float16*)d_ws;
    _Float16* Bl  = Bh + nB;
    _Float16* H16 = Bl + nB;

    prep_fused<<<dim3(128 + ZEROB + CONVB), dim3(256), 0, stream>>>(
        RW, dside, Wrel, hmat, Bh, Bl, H16, out);

    dim3 grid(NBX, NCH);
    edge_kernel<<<grid, dim3(512), 0, stream>>>(H16, src, dst, brel, Bh, Bl, out);
}